// Round 1
// baseline (1269.257 us; speedup 1.0000x reference)
//
#include <hip/hip_runtime.h>
#include <math.h>

#define D_MODEL 1024
#define NHEADS  16
#define DK      64
#define SEQ     2048
#define BATCH   2
#define MROWS   (BATCH*SEQ)   // 4096

// ---------------------------------------------------------------------------
// GEMM: C[M,N] = A[M,K] @ W[N,K]^T + bias[N]   (torch Linear layout)
// 64x64 block tile, 256 threads, 4x4 microtile per thread, K-tile = 16.
// ---------------------------------------------------------------------------
__global__ __launch_bounds__(256) void gemm_xwt(
    const float* __restrict__ A, const float* __restrict__ W,
    const float* __restrict__ bias, float* __restrict__ C,
    int M, int N, int K)
{
    __shared__ float As[16][68];   // [k][m], pad 68 keeps float4 alignment
    __shared__ float Ws[16][68];   // [k][n]
    const int tid = threadIdx.x;
    const int tx = tid & 15, ty = tid >> 4;
    const int bm = blockIdx.x * 64;
    const int bn = blockIdx.y * 64;

    float acc[4][4] = {};

    for (int k0 = 0; k0 < K; k0 += 16) {
        __syncthreads();
#pragma unroll
        for (int l = 0; l < 4; ++l) {
            int idx = tid + l * 256;        // 0..1023
            int k = idx & 15;
            int m = idx >> 4;
            As[k][m] = A[(size_t)(bm + m) * K + k0 + k];
            Ws[k][m] = W[(size_t)(bn + m) * K + k0 + k];
        }
        __syncthreads();
#pragma unroll
        for (int k = 0; k < 16; ++k) {
            float4 av = *(const float4*)&As[k][ty * 4];
            float4 wv = *(const float4*)&Ws[k][tx * 4];
            float a[4] = {av.x, av.y, av.z, av.w};
            float w[4] = {wv.x, wv.y, wv.z, wv.w};
#pragma unroll
            for (int i = 0; i < 4; ++i)
#pragma unroll
                for (int j = 0; j < 4; ++j)
                    acc[i][j] = fmaf(a[i], w[j], acc[i][j]);
        }
    }

#pragma unroll
    for (int i = 0; i < 4; ++i) {
        int m = bm + ty * 4 + i;
#pragma unroll
        for (int j = 0; j < 4; ++j) {
            int n = bn + tx * 4 + j;
            C[(size_t)m * N + n] = acc[i][j] + bias[n];
        }
    }
}

// ---------------------------------------------------------------------------
// Causal flash attention, fp32.  Grid: (SEQ/64 q-tiles, BATCH*NHEADS).
// Q,K stored transposed in LDS ([d][row]) for float4 fragment reads.
// ---------------------------------------------------------------------------
__global__ __launch_bounds__(256) void flash_attn(
    const float* __restrict__ Qp, const float* __restrict__ Kp,
    const float* __restrict__ Vp, float* __restrict__ Hc)
{
    const int qt = blockIdx.x;           // q tile 0..31
    const int bh = blockIdx.y;           // 0..31
    const int b = bh >> 4, h = bh & 15;
    const int tid = threadIdx.x;
    const int tx = tid & 15, ty = tid >> 4;

    __shared__ float Qs[DK][68];   // [d][r]
    __shared__ float Ks[DK][68];   // [d][c]
    __shared__ float Vs[64][68];   // [k][c]
    __shared__ float Ss[64][68];   // [r][c]  (scores -> probs)
    __shared__ float mrow[64], lrow[64], arow[64];

    const size_t base = (size_t)(b * SEQ) * D_MODEL + h * DK;

    // load Q tile (transposed)
#pragma unroll
    for (int l = 0; l < 16; ++l) {
        int idx = tid + l * 256;         // 0..4095
        int d = idx & 63, r = idx >> 6;
        Qs[d][r] = Qp[base + (size_t)(qt * 64 + r) * D_MODEL + d];
    }
    if (tid < 64) { mrow[tid] = -INFINITY; lrow[tid] = 0.f; }

    float o[4][4] = {};

    for (int kt = 0; kt <= qt; ++kt) {
        __syncthreads();
#pragma unroll
        for (int l = 0; l < 16; ++l) {
            int idx = tid + l * 256;
            int d = idx & 63, r = idx >> 6;
            float kv = Kp[base + (size_t)(kt * 64 + r) * D_MODEL + d];
            float vv = Vp[base + (size_t)(kt * 64 + r) * D_MODEL + d];
            Ks[d][r] = kv;
            Vs[r][d] = vv;
        }
        __syncthreads();

        // S = (Q K^T) * scale, causal mask on diagonal tile
        float s[4][4] = {};
#pragma unroll 8
        for (int d = 0; d < DK; ++d) {
            float4 qa = *(const float4*)&Qs[d][ty * 4];
            float4 kb = *(const float4*)&Ks[d][tx * 4];
            float a[4] = {qa.x, qa.y, qa.z, qa.w};
            float c[4] = {kb.x, kb.y, kb.z, kb.w};
#pragma unroll
            for (int i = 0; i < 4; ++i)
#pragma unroll
                for (int j = 0; j < 4; ++j)
                    s[i][j] = fmaf(a[i], c[j], s[i][j]);
        }
#pragma unroll
        for (int i = 0; i < 4; ++i) {
            int r = ty * 4 + i;
            float v[4];
#pragma unroll
            for (int j = 0; j < 4; ++j) {
                float val = s[i][j] * 0.125f;       // 1/sqrt(64)
                if (kt == qt && (tx * 4 + j) > r) val = -INFINITY;
                v[j] = val;
            }
            *(float4*)&Ss[r][tx * 4] = make_float4(v[0], v[1], v[2], v[3]);
        }
        __syncthreads();

        // online softmax row update (one thread per row)
        if (tid < 64) {
            int r = tid;
            float tm = -INFINITY;
            for (int c = 0; c < 64; ++c) tm = fmaxf(tm, Ss[r][c]);
            float mold = mrow[r];
            float mnew = fmaxf(mold, tm);
            float alpha = expf(mold - mnew);        // 0 when mold = -inf
            float sum = 0.f;
            for (int c = 0; c < 64; ++c) {
                float p = expf(Ss[r][c] - mnew);
                Ss[r][c] = p;
                sum += p;
            }
            lrow[r] = lrow[r] * alpha + sum;
            mrow[r] = mnew;
            arow[r] = alpha;
        }
        __syncthreads();

        // O = O*alpha + P @ V
        float al[4];
#pragma unroll
        for (int i = 0; i < 4; ++i) al[i] = arow[ty * 4 + i];
#pragma unroll
        for (int i = 0; i < 4; ++i)
#pragma unroll
            for (int j = 0; j < 4; ++j) o[i][j] *= al[i];

#pragma unroll 8
        for (int k = 0; k < 64; ++k) {
            float4 vb = *(const float4*)&Vs[k][tx * 4];
            float vv[4] = {vb.x, vb.y, vb.z, vb.w};
            float p[4];
#pragma unroll
            for (int i = 0; i < 4; ++i) p[i] = Ss[ty * 4 + i][k];
#pragma unroll
            for (int i = 0; i < 4; ++i)
#pragma unroll
                for (int j = 0; j < 4; ++j)
                    o[i][j] = fmaf(p[i], vv[j], o[i][j]);
        }
    }

    // epilogue: divide by l, write Hcat in [B,S,D] layout
#pragma unroll
    for (int i = 0; i < 4; ++i) {
        int r = ty * 4 + i;
        float invl = 1.f / lrow[r];
#pragma unroll
        for (int j = 0; j < 4; ++j) {
            Hc[base + (size_t)(qt * 64 + r) * D_MODEL + tx * 4 + j] = o[i][j] * invl;
        }
    }
}

extern "C" void kernel_launch(void* const* d_in, const int* in_sizes, int n_in,
                              void* d_out, int out_size, void* d_ws, size_t ws_size,
                              hipStream_t stream) {
    const float* inQ = (const float*)d_in[0];
    const float* inK = (const float*)d_in[1];
    const float* inV = (const float*)d_in[2];
    const float* Wq  = (const float*)d_in[3];
    const float* bq  = (const float*)d_in[4];
    const float* Wk  = (const float*)d_in[5];
    const float* bk  = (const float*)d_in[6];
    const float* Wv  = (const float*)d_in[7];
    const float* bv  = (const float*)d_in[8];
    const float* Wo  = (const float*)d_in[9];
    const float* bo  = (const float*)d_in[10];
    float* out = (float*)d_out;

    float* ws = (float*)d_ws;
    const size_t MK = (size_t)MROWS * D_MODEL;   // 4M floats = 16 MB
    float* Qp = ws;
    float* Kp = ws + MK;
    float* Vp = ws + 2 * MK;
    float* Hc = ws + 3 * MK;

    dim3 gg(MROWS / 64, D_MODEL / 64);
    gemm_xwt<<<gg, 256, 0, stream>>>(inQ, Wq, bq, Qp, MROWS, D_MODEL, D_MODEL);
    gemm_xwt<<<gg, 256, 0, stream>>>(inK, Wk, bk, Kp, MROWS, D_MODEL, D_MODEL);
    gemm_xwt<<<gg, 256, 0, stream>>>(inV, Wv, bv, Vp, MROWS, D_MODEL, D_MODEL);

    dim3 ga(SEQ / 64, BATCH * NHEADS);
    flash_attn<<<ga, 256, 0, stream>>>(Qp, Kp, Vp, Hc);

    gemm_xwt<<<gg, 256, 0, stream>>>(Hc, Wo, bo, out, MROWS, D_MODEL, D_MODEL);
}